// Round 11
// baseline (256.493 us; speedup 1.0000x reference)
//
#include <hip/hip_runtime.h>

static constexpr int T_LEN = 1024;

typedef _Float16 f16;
typedef f16  f16x4 __attribute__((ext_vector_type(4)));
typedef float f32x4 __attribute__((ext_vector_type(4)));

__device__ __forceinline__ f32x4 mfma16(f16x4 a, f16x4 b, f32x4 c) {
    return __builtin_amdgcn_mfma_f32_16x16x16f16(a, b, c, 0, 0, 0);
}
// 1/(1+2^t): overflow-safe (t->+inf: exp2=inf, rcp->0; t->-inf: ->1)
__device__ __forceinline__ float sig2(float t) {
    return __builtin_amdgcn_rcpf(1.f + __builtin_amdgcn_exp2f(t));
}

// 8 waves (512 thr) per block, 16 seqs per block, 256 blocks = 2 waves/SIMD.
// Wave w8 = lyr*4+q owns layer lyr, unit-block q (units 4q..4q+3).
// ROW-INTERLEAVED A-fragments (round-10-verified): tile-row m = gate(m&3) of
// unit(4q + (m>>2)); with the D-layout each lane's f32x4 D = (i,f,g,o) of ONE
// unit (u1 = 4q + (lane>>4)) for its seq (lane&15) -> lane-local LSTM update.
// Only h is exchanged through double-buffered LDS, ONE barrier per step.
//
// Round-11 deltas:
//  - exchange stride 40B -> 72B (36 f16): dword stride 18 gives 16 distinct
//    mixed-parity bank bases (18n%32) -> reads ~2-way (free) instead of
//    4-way-on-even-banks; h1 (elems 0-15) and h2 (elems 16-31) colocated per
//    seq so L2's two b64 reads are 32B apart (ds_read2_b64-fusable).
//  - static s_setprio(1) for L2 waves (the stragglers: 2 MFMAs + 2 reads);
//    CU scheduler favors them, shrinking the all-wave barrier wait.
__global__ void __launch_bounds__(512, 1) lstm2_unit2_kernel(
    const float* __restrict__ x,
    const float* __restrict__ Wih0, const float* __restrict__ Whh0,
    const float* __restrict__ bih0, const float* __restrict__ bhh0,
    const float* __restrict__ Wih1, const float* __restrict__ Whh1,
    const float* __restrict__ bih1, const float* __restrict__ bhh1,
    const float* __restrict__ Wout, const float* __restrict__ bout,
    float* __restrict__ out)
{
    const int tid = threadIdx.x;
    const int w8  = tid >> 6;          // lyr*4 + q
    const int lyr = w8 >> 2;
    const int q   = w8 & 3;
    const int l   = tid & 63;
    const int n   = l & 15;            // seq col (B/D); A tile-row
    const int Lq  = l >> 4;            // lane quad
    const int seq = blockIdx.x * 16 + n;

    // h exchange: [slot][seq][36 f16] = 72B row stride (dword stride 18).
    // elems 0-15: h1 units; elems 16-31: h2 units; 32-35 pad.
    __shared__ __align__(16) f16   hx[2][16][36];
    __shared__ __align__(16) float h2fin[16][20];

    if (lyr == 1) __builtin_amdgcn_s_setprio(1);   // L2 = straggler class

    const float L2E = 1.442695041f;
    const float NT  = -2.f * L2E;      // tanh(c) scale

    // A rows (tile-row m = lane&15): gate m&3, unit 4q + (m>>2).
    const int   gA    = n & 3;
    const int   wrowA = gA * 16 + 4 * q + (n >> 2);
    const float nsA   = (gA == 2) ? (-2.f * L2E) : (-L2E);
    // D rows (reg r): gate r, unit u1 = 4q + Lq.
    const int   u1    = 4 * q + Lq;

    f16x4 WaA = {}, WaB = {};          // L1: Whh0 ; L2: Wih1, Whh1
    f32x4 cbD, wxD = {};               // D-layout: bias, Wih0 (L1 only)
#pragma unroll
    for (int r = 0; r < 4; ++r) {
        const float nsD  = (r == 2) ? (-2.f * L2E) : (-L2E);
        const int   wrdD = r * 16 + u1;
        if (lyr == 0) {
            WaA[r] = (f16)(nsA * Whh0[wrowA * 16 + 4 * Lq + r]);
            cbD[r] = nsD * (bih0[wrdD] + bhh0[wrdD]);
            wxD[r] = nsD * Wih0[wrdD];
        } else {
            WaA[r] = (f16)(nsA * Wih1[wrowA * 16 + 4 * Lq + r]);
            WaB[r] = (f16)(nsA * Whh1[wrowA * 16 + 4 * Lq + r]);
            cbD[r] = nsD * (bih1[wrdD] + bhh1[wrdD]);
        }
    }
    asm volatile("" : "+v"(WaA), "+v"(WaB), "+v"(cbD), "+v"(wxD));

    f16x4 h1f = {}, h2f = {};          // h1[t-1], h2[t-2] (B layout)
    float c1 = 0.f, c2 = 0.f;          // this lane's unit state
    f32x4 pre2 = cbD;                  // L2: Whh1·h2[t-2] + b2 (h2[-1]=0)

    const float* xb = x + (size_t)seq * T_LEN;
    float4 xq = make_float4(0.f, 0.f, 0.f, 0.f);
    if (lyr == 0) xq = *reinterpret_cast<const float4*>(xb);

    for (int tb = 0; tb < T_LEN; tb += 4) {
        float4 xn = xq;
        if (lyr == 0 && tb + 4 < T_LEN)
            xn = *reinterpret_cast<const float4*>(xb + tb + 4);
#pragma unroll
        for (int u = 0; u < 4; ++u) {
            const int   t    = tb + u;
            const int   slot = u & 1;          // == t&1
            const float xv   = (u==0)?xq.x:(u==1)?xq.y:(u==2)?xq.z:xq.w;

            if (lyr == 0) {
                // ---- L1 step t: gates of units 4q..4q+3 (this lane: u1)
                f32x4 ci;
#pragma unroll
                for (int r = 0; r < 4; ++r)
                    ci[r] = fmaf(wxD[r], xv, cbD[r]);
                const f32x4 d = mfma16(WaA, h1f, ci);
                const float si = sig2(d[0]);
                const float sf = sig2(d[1]);
                const float sg = fmaf(2.f, sig2(d[2]), -1.f);
                const float so = sig2(d[3]);
                c1 = fmaf(sf, c1, si * sg);
                const float th = fmaf(2.f, sig2(NT * c1), -1.f);
                hx[slot][n][u1] = (f16)(so * th);
            } else if (t >= 1) {
                // ---- L2 step t-1: gb = Wih1·h1[t-1] + pre2
                const f32x4 d = mfma16(WaA, h1f, pre2);
                const float si = sig2(d[0]);
                const float sf = sig2(d[1]);
                const float sg = fmaf(2.f, sig2(d[2]), -1.f);
                const float so = sig2(d[3]);
                c2 = fmaf(sf, c2, si * sg);
                const float th = fmaf(2.f, sig2(NT * c2), -1.f);
                hx[slot][n][16 + u1] = (f16)(so * th);
            }
            __syncthreads();

            // ---- pick up the freshly exchanged h
            h1f = *reinterpret_cast<const f16x4*>(&hx[slot][n][4 * Lq]);
            if (lyr == 1 && t >= 1) {
                h2f = *reinterpret_cast<const f16x4*>(&hx[slot][n][16 + 4 * Lq]);
                pre2 = mfma16(WaB, h2f, cbD);   // for iter t+1 (off-path)
            }
        }
        xq = xn;
    }

    // ---- epilogue: L2 step T-1 (h1f = h1[T-1], pre2 = Whh1·h2[T-2]+b2)
    if (lyr == 1) {
        const f32x4 d = mfma16(WaA, h1f, pre2);
        const float si = sig2(d[0]);
        const float sf = sig2(d[1]);
        const float sg = fmaf(2.f, sig2(d[2]), -1.f);
        const float so = sig2(d[3]);
        c2 = fmaf(sf, c2, si * sg);
        const float th = fmaf(2.f, sig2(NT * c2), -1.f);
        h2fin[n][u1] = so * th;                // f32 for the head
    }
    __syncthreads();

    // ---- head (wave 0): out[seq][m] = relu(h2) . Wout[m] + bout[m]
    if (w8 == 0) {
        const f32x4 hv = *reinterpret_cast<const f32x4*>(&h2fin[n][4 * Lq]);
#pragma unroll
        for (int m5 = 0; m5 < 5; ++m5) {
            float p = 0.f;
#pragma unroll
            for (int r = 0; r < 4; ++r)
                p = fmaf(fmaxf(hv[r], 0.f), Wout[m5 * 16 + 4 * Lq + r], p);
            p += __shfl_xor(p, 16, 64);
            p += __shfl_xor(p, 32, 64);
            if (Lq == 0) out[seq * 5 + m5] = p + bout[m5];
        }
    }
}

extern "C" void kernel_launch(void* const* d_in, const int* in_sizes, int n_in,
                              void* d_out, int out_size, void* d_ws, size_t ws_size,
                              hipStream_t stream) {
    const float* x    = (const float*)d_in[0];
    const float* Wih0 = (const float*)d_in[1];
    const float* Whh0 = (const float*)d_in[2];
    const float* bih0 = (const float*)d_in[3];
    const float* bhh0 = (const float*)d_in[4];
    const float* Wih1 = (const float*)d_in[5];
    const float* Whh1 = (const float*)d_in[6];
    const float* bih1 = (const float*)d_in[7];
    const float* bhh1 = (const float*)d_in[8];
    const float* Wout = (const float*)d_in[9];
    const float* bout = (const float*)d_in[10];
    float* out = (float*)d_out;

    const int B = in_sizes[0] / T_LEN;          // 4096
    dim3 grid(B / 16), block(512);              // 8 waves / 16 seqs per block
    hipLaunchKernelGGL(lstm2_unit2_kernel, grid, block, 0, stream,
                       x, Wih0, Whh0, bih0, bhh0,
                       Wih1, Whh1, bih1, bhh1, Wout, bout, out);
}

// Round 12
// 253.783 us; speedup vs baseline: 1.0107x; 1.0107x over previous
//
#include <hip/hip_runtime.h>

static constexpr int T_LEN = 1024;

typedef _Float16 f16;
typedef f16  f16x4 __attribute__((ext_vector_type(4)));
typedef float f32x4 __attribute__((ext_vector_type(4)));

__device__ __forceinline__ f32x4 mfma16(f16x4 a, f16x4 b, f32x4 c) {
    return __builtin_amdgcn_mfma_f32_16x16x16f16(a, b, c, 0, 0, 0);
}
// 1/(1+2^t): overflow-safe (t->+inf: exp2=inf, rcp->0; t->-inf: ->1)
__device__ __forceinline__ float sig2(float t) {
    return __builtin_amdgcn_rcpf(1.f + __builtin_amdgcn_exp2f(t));
}

// 8 waves (512 thr) per block, 16 seqs per block, 256 blocks = 2 waves/SIMD.
// Wave w8 = lyr*4+q owns layer lyr, unit-block q (units 4q..4q+3).
// ROW-INTERLEAVED A-fragments (round-10-verified): tile-row m = gate(m&3) of
// unit(4q + (m>>2)); with the D-layout each lane's f32x4 D = (i,f,g,o) of ONE
// unit (u1 = 4q + (lane>>4)) for its seq (lane&15) -> lane-local LSTM update.
// Only h is exchanged through double-buffered LDS, ONE barrier per step.
//
// Round-12 delta: ZERO VMEM IN THE T-LOOP. __syncthreads emits
// s_waitcnt vmcnt(0) before s_barrier, so the old in-loop global x prefetch
// was force-drained at every u=0 barrier (HBM-latency straggler stalls all
// 8 waves collectively). x is now staged to LDS once (f16, coalesced) and
// read via ds_read_b64 — covered by the barrier's lgkmcnt(0) for free.
__global__ void __launch_bounds__(512, 1) lstm2_xlds_kernel(
    const float* __restrict__ x,
    const float* __restrict__ Wih0, const float* __restrict__ Whh0,
    const float* __restrict__ bih0, const float* __restrict__ bhh0,
    const float* __restrict__ Wih1, const float* __restrict__ Whh1,
    const float* __restrict__ bih1, const float* __restrict__ bhh1,
    const float* __restrict__ Wout, const float* __restrict__ bout,
    float* __restrict__ out)
{
    const int tid = threadIdx.x;
    const int w8  = tid >> 6;          // lyr*4 + q
    const int lyr = w8 >> 2;
    const int q   = w8 & 3;
    const int l   = tid & 63;
    const int n   = l & 15;            // seq col (B/D); A tile-row
    const int Lq  = l >> 4;            // lane quad
    const int seq = blockIdx.x * 16 + n;

    // x tile, f16: row stride 1028 -> dword stride 514 (%32 == 2), so the 16
    // per-seq b64 reads cover all 32 banks exactly once (conflict-free).
    __shared__ __align__(16) f16   x_lds[16][1028];
    // h exchange: [slot][seq][36 f16]; elems 0-15 h1, 16-31 h2, 32-35 pad.
    __shared__ __align__(16) f16   hx[2][16][36];
    __shared__ __align__(16) float h2fin[16][20];

    // ---- stage x (f32 global -> f16 LDS), fully coalesced, once.
    {
        const float* xblk = x + (size_t)blockIdx.x * 16 * T_LEN;
#pragma unroll
        for (int jj = 0; jj < 8; ++jj) {
            const int flat = jj * 2048 + tid * 4;      // f32 quad index
            const int row  = flat >> 10, col = flat & 1023;
            const float4 v = *reinterpret_cast<const float4*>(xblk + (size_t)row * T_LEN + col);
            f16x4 h4; h4[0] = (f16)v.x; h4[1] = (f16)v.y;
                      h4[2] = (f16)v.z; h4[3] = (f16)v.w;
            *reinterpret_cast<f16x4*>(&x_lds[row][col]) = h4;
        }
    }

    const float L2E = 1.442695041f;
    const float NT  = -2.f * L2E;      // tanh(c) scale

    // A rows (tile-row m = lane&15): gate m&3, unit 4q + (m>>2).
    const int   gA    = n & 3;
    const int   wrowA = gA * 16 + 4 * q + (n >> 2);
    const float nsA   = (gA == 2) ? (-2.f * L2E) : (-L2E);
    // D rows (reg r): gate r, unit u1 = 4q + Lq.
    const int   u1    = 4 * q + Lq;

    f16x4 WaA = {}, WaB = {};          // L1: Whh0 ; L2: Wih1, Whh1
    f32x4 cbD, wxD = {};               // D-layout: bias, Wih0 (L1 only)
#pragma unroll
    for (int r = 0; r < 4; ++r) {
        const float nsD  = (r == 2) ? (-2.f * L2E) : (-L2E);
        const int   wrdD = r * 16 + u1;
        if (lyr == 0) {
            WaA[r] = (f16)(nsA * Whh0[wrowA * 16 + 4 * Lq + r]);
            cbD[r] = nsD * (bih0[wrdD] + bhh0[wrdD]);
            wxD[r] = nsD * Wih0[wrdD];
        } else {
            WaA[r] = (f16)(nsA * Wih1[wrowA * 16 + 4 * Lq + r]);
            WaB[r] = (f16)(nsA * Whh1[wrowA * 16 + 4 * Lq + r]);
            cbD[r] = nsD * (bih1[wrdD] + bhh1[wrdD]);
        }
    }
    asm volatile("" : "+v"(WaA), "+v"(WaB), "+v"(cbD), "+v"(wxD));

    f16x4 h1f = {}, h2f = {};          // h1[t-1], h2[t-2] (B layout)
    float c1 = 0.f, c2 = 0.f;          // this lane's unit state
    f32x4 pre2 = cbD;                  // L2: Whh1·h2[t-2] + b2 (h2[-1]=0)

    __syncthreads();                   // x staged; also orders weight loads

    f16x4 xq = {};
    if (lyr == 0) xq = *reinterpret_cast<const f16x4*>(&x_lds[n][0]);

    for (int tb = 0; tb < T_LEN; tb += 4) {
        f16x4 xn = xq;
        if (lyr == 0 && tb + 4 < T_LEN)
            xn = *reinterpret_cast<const f16x4*>(&x_lds[n][tb + 4]);
#pragma unroll
        for (int u = 0; u < 4; ++u) {
            const int   t    = tb + u;
            const int   slot = u & 1;          // == t&1

            if (lyr == 0) {
                // ---- L1 step t: gates of units 4q..4q+3 (this lane: u1)
                const float xv = (float)xq[u];
                f32x4 ci;
#pragma unroll
                for (int r = 0; r < 4; ++r)
                    ci[r] = fmaf(wxD[r], xv, cbD[r]);
                const f32x4 d = mfma16(WaA, h1f, ci);
                const float si = sig2(d[0]);
                const float sf = sig2(d[1]);
                const float sg = fmaf(2.f, sig2(d[2]), -1.f);
                const float so = sig2(d[3]);
                c1 = fmaf(sf, c1, si * sg);
                const float th = fmaf(2.f, sig2(NT * c1), -1.f);
                hx[slot][n][u1] = (f16)(so * th);
            } else if (t >= 1) {
                // ---- L2 step t-1: gb = Wih1·h1[t-1] + pre2
                const f32x4 d = mfma16(WaA, h1f, pre2);
                const float si = sig2(d[0]);
                const float sf = sig2(d[1]);
                const float sg = fmaf(2.f, sig2(d[2]), -1.f);
                const float so = sig2(d[3]);
                c2 = fmaf(sf, c2, si * sg);
                const float th = fmaf(2.f, sig2(NT * c2), -1.f);
                hx[slot][n][16 + u1] = (f16)(so * th);
            }
            __syncthreads();

            // ---- pick up the freshly exchanged h
            h1f = *reinterpret_cast<const f16x4*>(&hx[slot][n][4 * Lq]);
            if (lyr == 1 && t >= 1) {
                h2f = *reinterpret_cast<const f16x4*>(&hx[slot][n][16 + 4 * Lq]);
                pre2 = mfma16(WaB, h2f, cbD);   // for iter t+1 (off-path)
            }
        }
        xq = xn;
    }

    // ---- epilogue: L2 step T-1 (h1f = h1[T-1], pre2 = Whh1·h2[T-2]+b2)
    if (lyr == 1) {
        const f32x4 d = mfma16(WaA, h1f, pre2);
        const float si = sig2(d[0]);
        const float sf = sig2(d[1]);
        const float sg = fmaf(2.f, sig2(d[2]), -1.f);
        const float so = sig2(d[3]);
        c2 = fmaf(sf, c2, si * sg);
        const float th = fmaf(2.f, sig2(NT * c2), -1.f);
        h2fin[n][u1] = so * th;                // f32 for the head
    }
    __syncthreads();

    // ---- head (wave 0): out[seq][m] = relu(h2) . Wout[m] + bout[m]
    if (w8 == 0) {
        const f32x4 hv = *reinterpret_cast<const f32x4*>(&h2fin[n][4 * Lq]);
#pragma unroll
        for (int m5 = 0; m5 < 5; ++m5) {
            float p = 0.f;
#pragma unroll
            for (int r = 0; r < 4; ++r)
                p = fmaf(fmaxf(hv[r], 0.f), Wout[m5 * 16 + 4 * Lq + r], p);
            p += __shfl_xor(p, 16, 64);
            p += __shfl_xor(p, 32, 64);
            if (Lq == 0) out[seq * 5 + m5] = p + bout[m5];
        }
    }
}

extern "C" void kernel_launch(void* const* d_in, const int* in_sizes, int n_in,
                              void* d_out, int out_size, void* d_ws, size_t ws_size,
                              hipStream_t stream) {
    const float* x    = (const float*)d_in[0];
    const float* Wih0 = (const float*)d_in[1];
    const float* Whh0 = (const float*)d_in[2];
    const float* bih0 = (const float*)d_in[3];
    const float* bhh0 = (const float*)d_in[4];
    const float* Wih1 = (const float*)d_in[5];
    const float* Whh1 = (const float*)d_in[6];
    const float* bih1 = (const float*)d_in[7];
    const float* bhh1 = (const float*)d_in[8];
    const float* Wout = (const float*)d_in[9];
    const float* bout = (const float*)d_in[10];
    float* out = (float*)d_out;

    const int B = in_sizes[0] / T_LEN;          // 4096
    dim3 grid(B / 16), block(512);              // 8 waves / 16 seqs per block
    hipLaunchKernelGGL(lstm2_xlds_kernel, grid, block, 0, stream,
                       x, Wih0, Whh0, bih0, bhh0,
                       Wih1, Whh1, bih1, bhh1, Wout, bout, out);
}